// Round 18
// baseline (366.808 us; speedup 1.0000x reference)
//
#include <hip/hip_runtime.h>

#define B_SZ 2048
#define T_SZ 2048

using f32x2 = float __attribute__((ext_vector_type(2)));

// DPP move: result[lane] = src[perm(lane)] (quad_perm / row_ror patterns)
template<int CTRL>
__device__ __forceinline__ float dppf(float v) {
  int r = __builtin_amdgcn_update_dpp(0, __builtin_bit_cast(int, v), CTRL, 0xf, 0xf, true);
  return __builtin_bit_cast(float, r);
}

__device__ __forceinline__ f32x2 pkfma(f32x2 a, f32x2 b, f32x2 c) {
  return __builtin_elementwise_fma(a, b, c);
}

#define SSTR 264                  // stage step stride in dwords
#define SBUF (8 * SSTR)           // one window buffer (8 steps)

// R13 (best, 341 us) with ONE change: u is staged through LDS instead of a
// register double-buffer the compiler refused to keep (VGPR=52 proves it was
// re-loading u from global inside the step loop -> per-step vmcnt stall on
// the chain). Per window: 1 global_load_dword/lane issued 2 windows ahead,
// ds_write at the boundary, per-step ds_read_b64 (16-lane broadcast, static
// offsets, recurrence-independent -> compiler front-loads them). No barriers:
// each wave reads only its own LDS section, DS is in-order per wave.
__global__ __launch_bounds__(256, 1) void sss_kernel(
    const float* __restrict__ x0p, const float* __restrict__ up,
    const float* __restrict__ tfp, const float* __restrict__ thp,
    const float* __restrict__ tup, const float* __restrict__ typ,
    const float* __restrict__ W1p, const float* __restrict__ b1p,
    const float* __restrict__ W2p, const float* __restrict__ Whp,
    float* __restrict__ outp)
{
  __shared__ float stageF[2 * SBUF];   // output staging, dbuf by window parity
  __shared__ float uLds[2 * 256];      // u staging, dbuf by window parity

  const int tid  = threadIdx.x;
  const int lane = tid & 63;
  const int wv   = __builtin_amdgcn_readfirstlane((int)(tid >> 6));
  const int grp  = lane >> 4;              // 16-lane group = row within wave
  const int sl   = lane & 15;              // sub-lane within group
  const int k    = lane & 3;               // output channel
  const int b0   = blockIdx.x * 16 + wv * 4;
  const int b    = b0 + grp;               // this lane's batch row

  // ---- prologue ----
  // fold K = 2*log2(e) into W1/cc: tanh(a) = 1 - 2/(exp2(K*a)+1)
  const float K = 2.8853900817779268f;
  f32x2 w1_01[6], w1_23[6];
#pragma unroll
  for (int r = 0; r < 6; ++r) {
    w1_01[r] = f32x2{W1p[r * 64 + sl]      * K, W1p[r * 64 + sl + 16] * K};
    w1_23[r] = f32x2{W1p[r * 64 + sl + 32] * K, W1p[r * 64 + sl + 48] * K};
  }
  float ccs[4];
#pragma unroll
  for (int i = 0; i < 4; ++i) {
    const int u = sl + 16 * i;
    float t = b1p[u];
#pragma unroll
    for (int q = 0; q < 5; ++q) t = fmaf(tfp[q], W1p[(6 + q) * 64 + u], t);
    ccs[i] = t * K;
  }
  const f32x2 cc01 = f32x2{ccs[0], ccs[1]};
  const f32x2 cc23 = f32x2{ccs[2], ccs[3]};

  const float scale = tup[0] / typ[0];
  // select-free role mapping: wAB[i]={col[k],col[k^1]}, wCD[i]={col[k^2],col[k^3]}
  f32x2 wAB[4], wCD[4];
#pragma unroll
  for (int i = 0; i < 4; ++i) {
    const float4 w2r = ((const float4*)W2p)[sl + 16 * i];
    float col[4] = {w2r.x * scale, w2r.y * scale, w2r.z * scale, w2r.w * scale};
    wAB[i] = f32x2{col[k], col[k ^ 1]};
    wCD[i] = f32x2{col[k ^ 2], col[k ^ 3]};
  }

  const float whl = Whp[k];            // Wh[k][0]
  const float th  = thp[0];

  // per-lane clip bounds: channels 0..2 -> [0,10], channel 3 unbounded
  const float lo = (k == 3) ? -__builtin_inff() : 0.0f;
  const float hi = (k == 3) ?  __builtin_inff() : 10.0f;

  // per-lane state: xlane = x[k] (replicated per quad)
  float xlane = x0p[b * 4 + k];
  float x0v = dppf<0x00>(xlane);
  float x1v = dppf<0x55>(xlane);
  float x2v = dppf<0xAA>(xlane);
  float x3v = dppf<0xFF>(xlane);

  // y0 = h(x_0), UNCLAMPED (matches reference)
  float p0 = xlane * whl;
  p0 += dppf<0xB1>(p0);
  p0 += dppf<0x4E>(p0);
  float yv = p0 + th;

  const bool is4 = (sl == 4);

  // ---- staging / flush address setup (R13-proven) ----
  const int m   = sl;
  const int xr  = lane >> 4;
  const int t0  = m >> 1;
  const int k0  = (2 * m) & 3;
  const int rdoff = t0 * SSTR + wv * 64 + 16 * xr + k0;       // dwords
  const int yoff  = (lane & 7) * SSTR + wv * 64 + 16 * (lane >> 3) + 4;
  float2* gxp = (float2*)outp + (size_t)(b0 + (lane >> 4)) * (T_SZ * 2) + (lane & 15);
  float*  gyp = outp + (size_t)B_SZ * T_SZ * 4 + (size_t)(b0 + (lane >> 3)) * T_SZ + (lane & 7);

  // ---- u pipeline setup ----
  // writer: lane L supplies u[b0 + (L>>4)][chunk*16 + (L&15)] at uLds[p][wv*64+L]
  // reader (step jj): all of group grp read uLds[p][wv*64 + grp*16 + 2*jj]
  const float* ugl = up + (size_t)(b0 + (lane >> 4)) * (T_SZ * 2) + (lane & 15);
  const int NC = T_SZ / 8;
  // prologue: chunk 0 into parity-0 LDS; chunk 1 held in uprev
  uLds[tid] = ugl[0];
  float uprev = ugl[16];
  const int urd = wv * 64 + grp * 16;      // reader base (dwords)

  for (int c = 0; c < NC; ++c) {
    // issue chunk c+2 load now; consumed by ds_write one iteration later
    const int gn2 = (c + 2 < NC) ? c + 2 : NC - 1;
    const float unew = ugl[gn2 * 16];

    float* sw = &stageF[(c & 1) * SBUF + tid];     // this window's write base
    const float* ur = &uLds[(c & 1) * 256 + urd];  // this window's u base
#pragma unroll
    for (int jj = 0; jj < 8; ++jj) {
      // ---- capture PRE-update carry (x_step, y_step) into LDS ----
      const float vdata = is4 ? yv : xlane;
      sw[jj * SSTR] = vdata;                       // ds_write_b32, fire-forget

      // u from LDS: ds_read_b64, broadcast across the 16-lane group,
      // address static per jj (independent of recurrence -> issued early)
      const float2 uu = *(const float2*)&ur[2 * jj];
      const float u0 = uu.x;
      const float u1 = uu.y;
      const f32x2 u0p = f32x2{u0, u0};
      const f32x2 u1p = f32x2{u1, u1};

      // u-only part (x-independent, schedulable early), packed unit pairs
      const f32x2 b01 = pkfma(u1p, w1_01[5], pkfma(u0p, w1_01[4], cc01));
      const f32x2 b23 = pkfma(u1p, w1_23[5], pkfma(u0p, w1_23[4], cc23));

      // x-part: depth-3 after broadcast, packed
      const f32x2 x0s = f32x2{x0v, x0v};
      const f32x2 x1s = f32x2{x1v, x1v};
      const f32x2 x2s = f32x2{x2v, x2v};
      const f32x2 x3s = f32x2{x3v, x3v};
      const f32x2 mA01 = pkfma(x1s, w1_01[1], x0s * w1_01[0]);
      const f32x2 mB01 = pkfma(x3s, w1_01[3], x2s * w1_01[2]);
      const f32x2 a01  = (b01 + mA01) + mB01;
      const f32x2 mA23 = pkfma(x1s, w1_23[1], x0s * w1_23[0]);
      const f32x2 mB23 = pkfma(x3s, w1_23[3], x2s * w1_23[2]);
      const f32x2 a23  = (b23 + mA23) + mB23;

      // tanh(a) = 1 - 2/(exp2(acc)+1), 4 units
      float h[4];
      {
        const float av[4] = {a01[0], a01[1], a23[0], a23[1]};
#pragma unroll
        for (int i = 0; i < 4; ++i) {
          const float e  = __builtin_amdgcn_exp2f(av[i]);
          const float rr = __builtin_amdgcn_rcpf(e + 1.0f);
          h[i] = fmaf(-2.0f, rr, 1.0f);
        }
      }
      const f32x2 h0s = f32x2{h[0], h[0]};
      const f32x2 h1s = f32x2{h[1], h[1]};
      const f32x2 h2s = f32x2{h[2], h[2]};
      const f32x2 h3s = f32x2{h[3], h[3]};

      // fold 4 units into tree roles, packed (A,B) and (C,D)
      f32x2 qAB = h0s * wAB[0];
      qAB = pkfma(h1s, wAB[1], qAB);
      qAB = pkfma(h2s, wAB[2], qAB);
      qAB = pkfma(h3s, wAB[3], qAB);
      f32x2 qCD = h0s * wCD[0];
      qCD = pkfma(h1s, wCD[1], qCD);
      qCD = pkfma(h2s, wCD[2], qCD);
      qCD = pkfma(h3s, wCD[3], qCD);

      // select-free quad tree: xor1 (0xB1), xor2 (0x4E), xor3 = reverse (0x1B)
      float v = (qAB[0] + dppf<0xB1>(qAB[1]))
              + (dppf<0x4E>(qCD[0]) + dppf<0x1B>(qCD[1]));
      v += dppf<0x124>(v);                      // row_ror:4
      v += dppf<0x128>(v);                      // row_ror:8 -> full 64-unit sum

      // per-lane state update: w = pre-clip x_raw[k]
      const float w = xlane + v;
      xlane = __builtin_amdgcn_fmed3f(w, lo, hi);   // clip (channel 3 unbounded)

      // y from PRE-clip state: quad reduce of w*wh
      float p = w * whl;
      p += dppf<0xB1>(p);
      p += dppf<0x4E>(p);
      yv = __builtin_amdgcn_fmed3f(p + th, 0.0f, 10.0f);

      // broadcast clipped state for next step's matvec (within quad)
      x0v = dppf<0x00>(xlane);
      x1v = dppf<0x55>(xlane);
      x2v = dppf<0xAA>(xlane);
      x3v = dppf<0xFF>(xlane);
    }
    // ---- window flush: LDS transpose -> coalesced wide stores (R13-proven) ----
    {
      const int bb = (c & 1) * SBUF;
      const float2 xv = *(const float2*)&stageF[bb + rdoff];  // ds_read_b64
      *gxp = xv;                                              // dwordx2, coalesced
      if (lane < 32) {
        const float yy2 = stageF[bb + yoff];
        *gyp = yy2;
      }
      gxp += 16;   // 32 floats (8 steps x 4 ch) per row per window
      gyp += 8;
    }
    // ---- u pipeline: write chunk c+1 into the other parity buffer ----
    // (uprev was loaded one full iteration ago -> its vmcnt wait is free)
    uLds[((c + 1) & 1) * 256 + tid] = uprev;
    uprev = unew;
  }
}

extern "C" void kernel_launch(void* const* d_in, const int* in_sizes, int n_in,
                              void* d_out, int out_size, void* d_ws, size_t ws_size,
                              hipStream_t stream) {
  (void)in_sizes; (void)n_in; (void)out_size; (void)d_ws; (void)ws_size;
  sss_kernel<<<dim3(B_SZ / 16), dim3(256), 0, stream>>>(
      (const float*)d_in[0], (const float*)d_in[1], (const float*)d_in[2],
      (const float*)d_in[3], (const float*)d_in[4], (const float*)d_in[5],
      (const float*)d_in[6], (const float*)d_in[7], (const float*)d_in[8],
      (const float*)d_in[9], (float*)d_out);
}

// Round 19
// 340.671 us; speedup vs baseline: 1.0767x; 1.0767x over previous
//
#include <hip/hip_runtime.h>

#define B_SZ 2048
#define T_SZ 2048

using f32x16 = float __attribute__((ext_vector_type(16)));
using f32x2  = float __attribute__((ext_vector_type(2)));

// DPP move: result[lane] = src[perm(lane)] (quad_perm / row_ror patterns)
template<int CTRL>
__device__ __forceinline__ float dppf(float v) {
  int r = __builtin_amdgcn_update_dpp(0, __builtin_bit_cast(int, v), CTRL, 0xf, 0xf, true);
  return __builtin_bit_cast(float, r);
}

__device__ __forceinline__ f32x2 pkfma(f32x2 a, f32x2 b, f32x2 c) {
  return __builtin_elementwise_fma(a, b, c);
}

#define SSTR 264                  // stage step stride in dwords (256 lanes + pad)
#define SBUF (8 * SSTR)           // one window buffer (8 steps)

// Best-of-session kernel (R13, 341 us): R8/R12 math (4 rows/wave, 16-lane
// group = row, lane owns units sl,sl+16,sl+32,sl+48; packed f32x2, select-free
// quad tree + ror4/ror8, quad broadcast) with outputs staged per-step to LDS
// (ds_write_b32, static offset, no exec mask) and flushed per 8-step window
// as coalesced wide global stores — keeping store-WAR vmcnt waits off the
// per-step recurrence chain (the one lever that measurably worked).
__global__ __launch_bounds__(256, 1) void sss_kernel(
    const float* __restrict__ x0p, const float* __restrict__ up,
    const float* __restrict__ tfp, const float* __restrict__ thp,
    const float* __restrict__ tup, const float* __restrict__ typ,
    const float* __restrict__ W1p, const float* __restrict__ b1p,
    const float* __restrict__ W2p, const float* __restrict__ Whp,
    float* __restrict__ outp)
{
  __shared__ float stageF[2 * SBUF];   // double-buffered by window parity

  const int tid  = threadIdx.x;
  const int lane = tid & 63;
  const int wv   = __builtin_amdgcn_readfirstlane((int)(tid >> 6));
  const int grp  = lane >> 4;              // 16-lane group = row within wave
  const int sl   = lane & 15;              // sub-lane within group
  const int k    = lane & 3;               // output channel
  const int b0   = blockIdx.x * 16 + wv * 4;
  const int b    = b0 + grp;               // this lane's batch row

  // ---- prologue ----
  // fold K = 2*log2(e) into W1/cc: tanh(a) = 1 - 2/(exp2(K*a)+1)
  const float K = 2.8853900817779268f;
  f32x2 w1_01[6], w1_23[6];
#pragma unroll
  for (int r = 0; r < 6; ++r) {
    w1_01[r] = f32x2{W1p[r * 64 + sl]      * K, W1p[r * 64 + sl + 16] * K};
    w1_23[r] = f32x2{W1p[r * 64 + sl + 32] * K, W1p[r * 64 + sl + 48] * K};
  }
  float ccs[4];
#pragma unroll
  for (int i = 0; i < 4; ++i) {
    const int u = sl + 16 * i;
    float t = b1p[u];
#pragma unroll
    for (int q = 0; q < 5; ++q) t = fmaf(tfp[q], W1p[(6 + q) * 64 + u], t);
    ccs[i] = t * K;
  }
  const f32x2 cc01 = f32x2{ccs[0], ccs[1]};
  const f32x2 cc23 = f32x2{ccs[2], ccs[3]};

  const float scale = tup[0] / typ[0];
  // select-free role mapping: wAB[i]={col[k],col[k^1]}, wCD[i]={col[k^2],col[k^3]}
  f32x2 wAB[4], wCD[4];
#pragma unroll
  for (int i = 0; i < 4; ++i) {
    const float4 w2r = ((const float4*)W2p)[sl + 16 * i];
    float col[4] = {w2r.x * scale, w2r.y * scale, w2r.z * scale, w2r.w * scale};
    wAB[i] = f32x2{col[k], col[k ^ 1]};
    wCD[i] = f32x2{col[k ^ 2], col[k ^ 3]};
  }

  const float whl = Whp[k];            // Wh[k][0]
  const float th  = thp[0];

  // per-lane clip bounds: channels 0..2 -> [0,10], channel 3 unbounded
  const float lo = (k == 3) ? -__builtin_inff() : 0.0f;
  const float hi = (k == 3) ?  __builtin_inff() : 10.0f;

  // per-lane state: xlane = x[k] (replicated per quad)
  float xlane = x0p[b * 4 + k];
  float x0v = dppf<0x00>(xlane);
  float x1v = dppf<0x55>(xlane);
  float x2v = dppf<0xAA>(xlane);
  float x3v = dppf<0xFF>(xlane);

  // y0 = h(x_0), UNCLAMPED (matches reference)
  float p0 = xlane * whl;
  p0 += dppf<0xB1>(p0);
  p0 += dppf<0x4E>(p0);
  float yv = p0 + th;

  const bool is4 = (sl == 4);

  // ---- staging / flush address setup (all loop-invariant) ----
  // stage slot for (step t, block-lane wl): t*SSTR + wl ; wl = tid
  // x-flush: lane L reads (row r=L>>4, flat m=L&15 -> t0=m>>1, k0=(2m)&3)
  const int m   = sl;
  const int xr  = lane >> 4;
  const int t0  = m >> 1;
  const int k0  = (2 * m) & 3;
  const int rdoff = t0 * SSTR + wv * 64 + 16 * xr + k0;       // dwords
  const int yoff  = (lane & 7) * SSTR + wv * 64 + 16 * (lane >> 3) + 4;
  // coalesced output pointers
  float2* gxp = (float2*)outp + (size_t)(b0 + (lane >> 4)) * (T_SZ * 2) + (lane & 15);
  float*  gyp = outp + (size_t)B_SZ * T_SZ * 4 + (size_t)(b0 + (lane >> 3)) * T_SZ + (lane & 7);

  const f32x16* up16 = (const f32x16*)(up + (size_t)b * (T_SZ * 2)); // 8 steps/chunk
  f32x16 uch = up16[0];
  const int NC = T_SZ / 8;

  for (int c = 0; c < NC; ++c) {
    const int g = (c + 1 < NC) ? c + 1 : NC - 1;   // prefetch next chunk
    const f32x16 unx = up16[g];
    float* sw = &stageF[(c & 1) * SBUF + tid];     // this window's write base
#pragma unroll
    for (int jj = 0; jj < 8; ++jj) {
      // ---- capture PRE-update carry (x_step, y_step) into LDS ----
      const float vdata = is4 ? yv : xlane;
      sw[jj * SSTR] = vdata;                       // ds_write_b32, static offset

      const float u0 = uch[2 * jj];
      const float u1 = uch[2 * jj + 1];
      const f32x2 u0p = f32x2{u0, u0};
      const f32x2 u1p = f32x2{u1, u1};

      // u-only part (x-independent, schedulable early), packed unit pairs
      const f32x2 b01 = pkfma(u1p, w1_01[5], pkfma(u0p, w1_01[4], cc01));
      const f32x2 b23 = pkfma(u1p, w1_23[5], pkfma(u0p, w1_23[4], cc23));

      // x-part: depth-3 after broadcast, packed
      const f32x2 x0s = f32x2{x0v, x0v};
      const f32x2 x1s = f32x2{x1v, x1v};
      const f32x2 x2s = f32x2{x2v, x2v};
      const f32x2 x3s = f32x2{x3v, x3v};
      const f32x2 mA01 = pkfma(x1s, w1_01[1], x0s * w1_01[0]);
      const f32x2 mB01 = pkfma(x3s, w1_01[3], x2s * w1_01[2]);
      const f32x2 a01  = (b01 + mA01) + mB01;
      const f32x2 mA23 = pkfma(x1s, w1_23[1], x0s * w1_23[0]);
      const f32x2 mB23 = pkfma(x3s, w1_23[3], x2s * w1_23[2]);
      const f32x2 a23  = (b23 + mA23) + mB23;

      // tanh(a) = 1 - 2/(exp2(acc)+1), 4 units
      float h[4];
      {
        const float av[4] = {a01[0], a01[1], a23[0], a23[1]};
#pragma unroll
        for (int i = 0; i < 4; ++i) {
          const float e  = __builtin_amdgcn_exp2f(av[i]);
          const float rr = __builtin_amdgcn_rcpf(e + 1.0f);
          h[i] = fmaf(-2.0f, rr, 1.0f);
        }
      }
      const f32x2 h0s = f32x2{h[0], h[0]};
      const f32x2 h1s = f32x2{h[1], h[1]};
      const f32x2 h2s = f32x2{h[2], h[2]};
      const f32x2 h3s = f32x2{h[3], h[3]};

      // fold 4 units into tree roles, packed (A,B) and (C,D)
      f32x2 qAB = h0s * wAB[0];
      qAB = pkfma(h1s, wAB[1], qAB);
      qAB = pkfma(h2s, wAB[2], qAB);
      qAB = pkfma(h3s, wAB[3], qAB);
      f32x2 qCD = h0s * wCD[0];
      qCD = pkfma(h1s, wCD[1], qCD);
      qCD = pkfma(h2s, wCD[2], qCD);
      qCD = pkfma(h3s, wCD[3], qCD);

      // select-free quad tree: xor1 (0xB1), xor2 (0x4E), xor3 = reverse (0x1B)
      float v = (qAB[0] + dppf<0xB1>(qAB[1]))
              + (dppf<0x4E>(qCD[0]) + dppf<0x1B>(qCD[1]));
      v += dppf<0x124>(v);                      // row_ror:4
      v += dppf<0x128>(v);                      // row_ror:8 -> full 64-unit sum

      // per-lane state update: w = pre-clip x_raw[k]
      const float w = xlane + v;
      xlane = __builtin_amdgcn_fmed3f(w, lo, hi);   // clip (channel 3 unbounded)

      // y from PRE-clip state: quad reduce of w*wh
      float p = w * whl;
      p += dppf<0xB1>(p);
      p += dppf<0x4E>(p);
      yv = __builtin_amdgcn_fmed3f(p + th, 0.0f, 10.0f);

      // broadcast clipped state for next step's matvec (within quad)
      x0v = dppf<0x00>(xlane);
      x1v = dppf<0x55>(xlane);
      x2v = dppf<0xAA>(xlane);
      x3v = dppf<0xFF>(xlane);
    }
    // ---- window flush: LDS transpose -> coalesced wide stores ----
    {
      const int bb = (c & 1) * SBUF;
      const float2 xv = *(const float2*)&stageF[bb + rdoff];  // ds_read_b64
      *gxp = xv;                                              // dwordx2, coalesced
      if (lane < 32) {
        const float yy = stageF[bb + yoff];
        *gyp = yy;
      }
      gxp += 16;   // 32 floats (8 steps x 4 ch) per row per window
      gyp += 8;
    }
    uch = unx;
  }
}

extern "C" void kernel_launch(void* const* d_in, const int* in_sizes, int n_in,
                              void* d_out, int out_size, void* d_ws, size_t ws_size,
                              hipStream_t stream) {
  (void)in_sizes; (void)n_in; (void)out_size; (void)d_ws; (void)ws_size;
  sss_kernel<<<dim3(B_SZ / 16), dim3(256), 0, stream>>>(
      (const float*)d_in[0], (const float*)d_in[1], (const float*)d_in[2],
      (const float*)d_in[3], (const float*)d_in[4], (const float*)d_in[5],
      (const float*)d_in[6], (const float*)d_in[7], (const float*)d_in[8],
      (const float*)d_in[9], (float*)d_out);
}